// Round 2
// baseline (577.746 us; speedup 1.0000x reference)
//
#include <hip/hip_runtime.h>

// VectorQuantizer: x[16384][64] fp32, codebook[8192][64] fp32
// out = concat(discrete one-hot [16384][8192] fp32, quantized [16384][64] fp32)
// argmin_k ||x-c_k||^2 == argmax_k (x.c_k - 0.5||c_k||^2)
//
// r14 -> r15: revert RPB to 32 (r14 showed occupancy was never binding and
// doubled packed L2 traffic, +10us). New: phase-split zero-fill. The NT
// zero stores leave the compute loop entirely: each wave blasts its 256 KB
// slice of the one-hot region as a dense 256-store NT loop, with ORDER
// swapped by wave parity (odd waves blast->compute, even waves
// compute->blast). Per CU, half the waves saturate HBM write BW while the
// other half runs the MFMA loop whose s_waitcnt now counts loads ONLY --
// no NT store can sit between a frag load and its consuming MFMA, removing
// the vmcnt load/store coupling suspected to cost ~1.1us/tile.
// Compute loop: RPB=32, 4 waves x 2048 codes, depth-2 register prefetch of
// B-frags + cn2, in-block argmax + one-hot + fused quantized gather.
// Exact fp32 dots via fp16 hi/lo split, 16 MFMA terms, bit-identical order.

#define NROWS 16384
#define KCODES 8192
#define DDIM 64
#define RPB 32                    // rows per block
#define CWAVES 4                  // waves per block (256 threads)
#define WCODES (KCODES / CWAVES)  // 2048 codes per wave
#define WTILES (WCODES / 16)      // 128 tiles per wave

typedef float    f32x4 __attribute__((ext_vector_type(4)));
typedef _Float16 f16x8 __attribute__((ext_vector_type(8)));

// ---------------- kernel 0: fused pack + cn2 ----------------
// thread (Tg, L): code = Tg*16 + (L&15), k-slice = (L>>4)*8 (+32).
// packed[Tg][frag][lane]: frag 0=hi k0..31, 1=hi k32..63, 2=lo k0..31, 3=lo k32..63.
__global__ __launch_bounds__(256) void k_prep(const float* __restrict__ cb,
                                              f16x8* __restrict__ packed,
                                              float* __restrict__ cn2) {
    int tid = blockIdx.x * 256 + threadIdx.x;   // 0..32767
    int Tg = tid >> 6, L = tid & 63;
    int lane15 = L & 15, quad = L >> 4;
    int code = Tg * 16 + lane15;
    const float* p = cb + (size_t)code * DDIM + quad * 8;
    f16x8 h0, l0, h1, l1;
    float s = 0.f;
#pragma unroll
    for (int j = 0; j < 8; ++j) {
        float v = p[j];
        _Float16 h = (_Float16)v;
        h0[j] = h; l0[j] = (_Float16)(v - (float)h);
        s = fmaf(v, v, s);
        float w = p[32 + j];
        _Float16 h2 = (_Float16)w;
        h1[j] = h2; l1[j] = (_Float16)(w - (float)h2);
        s = fmaf(w, w, s);
    }
    s += __shfl_xor(s, 16, 64);
    s += __shfl_xor(s, 32, 64);
    if (quad == 0) cn2[code] = 0.5f * s;
    f16x8* out = packed + (size_t)Tg * 256 + L;
    out[0]   = h0;
    out[64]  = h1;
    out[128] = l0;
    out[192] = l1;
}

// ---------------- kernel 1: MFMA + argmax + phase-split NT zero-fill ----------------
__global__ __launch_bounds__(256, 4) void k_main(const float* __restrict__ x,
                                                 const float* __restrict__ cb,
                                                 const f16x8* __restrict__ packed,
                                                 const float* __restrict__ cn2,
                                                 float* __restrict__ discrete,
                                                 float* __restrict__ quantized) {
    const int t = threadIdx.x;
    const int L = t & 63;
    const int w = t >> 6;                 // wave = code quarter (ascending codes)
    const int row0 = blockIdx.x * RPB;
    const int lane15 = L & 15;
    const int quad = L >> 4;

    // ---- A fragments: two row groups, exact hi/lo split ----
    const float* xa = x + (size_t)(row0 + lane15) * DDIM + quad * 8;
    const float* xb = xa + 16 * DDIM;
    f16x8 Ah0, Al0, Ah1, Al1, Bh0, Bl0, Bh1, Bl1;
#pragma unroll
    for (int j = 0; j < 8; ++j) {
        float v = xa[j];        _Float16 h = (_Float16)v;
        Ah0[j] = h; Al0[j] = (_Float16)(v - (float)h);
        v = xa[32 + j];         h = (_Float16)v;
        Ah1[j] = h; Al1[j] = (_Float16)(v - (float)h);
        v = xb[j];              h = (_Float16)v;
        Bh0[j] = h; Bl0[j] = (_Float16)(v - (float)h);
        v = xb[32 + j];         h = (_Float16)v;
        Bh1[j] = h; Bl1[j] = (_Float16)(v - (float)h);
    }

    float bvA[4], bvB[4];
    int   biA[4], biB[4];
#pragma unroll
    for (int r = 0; r < 4; ++r) { bvA[r] = bvB[r] = -3.4e38f; biA[r] = biB[r] = 0; }

    const int code0 = w * WCODES;
    f32x4* zdst = (f32x4*)(discrete + (size_t)row0 * KCODES);   // 65536 f32x4/block

    // ---- dense NT zero blast: wave w covers f32x4 [w*16384, (w+1)*16384) ----
    // 256 stores/thread, 1 KB contiguous per wave-store, no waits needed.
    auto zero_blast = [&]() {
        const f32x4 zero4 = {0.f, 0.f, 0.f, 0.f};
        f32x4* zp = zdst + (w << 14) + L;
#pragma unroll 8
        for (int j = 0; j < 256; ++j)
            __builtin_nontemporal_store(zero4, zp + j * 64);
    };

    // ---- MFMA + argmax loop, loads only (no stores -> clean vmcnt) ----
    auto compute = [&]() {
        const f16x8* pbase = packed + (size_t)(code0 >> 4) * 256 + L;
        // preload tiles 0 (cur) and 1 (nxt): B frags + cn
        f16x8 ch0 = pbase[0], ch1 = pbase[64], cl0 = pbase[128], cl1 = pbase[192];
        float cn = cn2[code0 + lane15];
        const f16x8* p1 = pbase + 256;
        f16x8 nh0 = p1[0], nh1 = p1[64], nl0 = p1[128], nl1 = p1[192];
        float cnn = cn2[code0 + 16 + lane15];

        for (int i = 0; i < WTILES; ++i) {
            // prefetch tile i+2 (depth-2 reach covers L2 latency)
            const int i2 = (i + 2 < WTILES) ? i + 2 : WTILES - 1;
            const f16x8* pm = pbase + (size_t)i2 * 256;
            f16x8 mh0 = pm[0], mh1 = pm[64], ml0 = pm[128], ml1 = pm[192];
            float cnm = cn2[code0 + i2 * 16 + lane15];

            // compute current tile (order bit-identical to r13)
            f32x4 accA = {-cn, -cn, -cn, -cn};
            f32x4 accB = accA;
            accA = __builtin_amdgcn_mfma_f32_16x16x32_f16(Ah0, ch0, accA, 0, 0, 0);
            accB = __builtin_amdgcn_mfma_f32_16x16x32_f16(Bh0, ch0, accB, 0, 0, 0);
            accA = __builtin_amdgcn_mfma_f32_16x16x32_f16(Ah1, ch1, accA, 0, 0, 0);
            accB = __builtin_amdgcn_mfma_f32_16x16x32_f16(Bh1, ch1, accB, 0, 0, 0);
            accA = __builtin_amdgcn_mfma_f32_16x16x32_f16(Al0, ch0, accA, 0, 0, 0);
            accB = __builtin_amdgcn_mfma_f32_16x16x32_f16(Bl0, ch0, accB, 0, 0, 0);
            accA = __builtin_amdgcn_mfma_f32_16x16x32_f16(Al1, ch1, accA, 0, 0, 0);
            accB = __builtin_amdgcn_mfma_f32_16x16x32_f16(Bl1, ch1, accB, 0, 0, 0);
            accA = __builtin_amdgcn_mfma_f32_16x16x32_f16(Ah0, cl0, accA, 0, 0, 0);
            accB = __builtin_amdgcn_mfma_f32_16x16x32_f16(Bh0, cl0, accB, 0, 0, 0);
            accA = __builtin_amdgcn_mfma_f32_16x16x32_f16(Ah1, cl1, accA, 0, 0, 0);
            accB = __builtin_amdgcn_mfma_f32_16x16x32_f16(Bh1, cl1, accB, 0, 0, 0);
            accA = __builtin_amdgcn_mfma_f32_16x16x32_f16(Al0, cl0, accA, 0, 0, 0);
            accB = __builtin_amdgcn_mfma_f32_16x16x32_f16(Bl0, cl0, accB, 0, 0, 0);
            accA = __builtin_amdgcn_mfma_f32_16x16x32_f16(Al1, cl1, accA, 0, 0, 0);
            accB = __builtin_amdgcn_mfma_f32_16x16x32_f16(Bl1, cl1, accB, 0, 0, 0);

            const int vcode = code0 + i * 16 + lane15;
#pragma unroll
            for (int r = 0; r < 4; ++r) {
                if (accA[r] > bvA[r]) { bvA[r] = accA[r]; biA[r] = vcode; }
                if (accB[r] > bvB[r]) { bvB[r] = accB[r]; biB[r] = vcode; }
            }

            // rotate pipeline stages
            ch0 = nh0; ch1 = nh1; cl0 = nl0; cl1 = nl1; cn = cnn;
            nh0 = mh0; nh1 = mh1; nl0 = ml0; nl1 = ml1; cnn = cnm;
        }
    };

    // ---- wave-parity phase schedule: half the CU's waves saturate HBM
    //      writes while the other half runs the load/MFMA loop ----
    if (w & 1) { zero_blast(); compute(); }
    else       { compute(); zero_blast(); }

    // ---- 16-lane butterfly per quad, then cross-wave LDS reduce ----
    __shared__ float rv[RPB][CWAVES + 1];
    __shared__ int   ri[RPB][CWAVES + 1];
    __shared__ int   sidx[RPB];
#pragma unroll
    for (int r = 0; r < 4; ++r) {
        float vA = bvA[r], vB = bvB[r];
        int  iA = biA[r], iB = biB[r];
#pragma unroll
        for (int m = 1; m < 16; m <<= 1) {
            float oA = __shfl_xor(vA, m, 64); int xA = __shfl_xor(iA, m, 64);
            if (oA > vA || (oA == vA && xA < iA)) { vA = oA; iA = xA; }
            float oB = __shfl_xor(vB, m, 64); int xB = __shfl_xor(iB, m, 64);
            if (oB > vB || (oB == vB && xB < iB)) { vB = oB; iB = xB; }
        }
        if (lane15 == 0) {
            rv[quad * 4 + r][w] = vA;      ri[quad * 4 + r][w] = iA;
            rv[16 + quad * 4 + r][w] = vB; ri[16 + quad * 4 + r][w] = iB;
        }
    }
    __syncthreads();   // drains NT zero stores before the 1.0 write
    if (t < RPB) {
        float bv = rv[t][0];
        int   bi = ri[t][0];
#pragma unroll
        for (int w2 = 1; w2 < CWAVES; ++w2) {  // ascending wave = ascending codes
            float v = rv[t][w2];
            int  id = ri[t][w2];
            if (v > bv || (v == bv && id < bi)) { bv = v; bi = id; }
        }
        int row = row0 + t;
        sidx[t] = bi;
        discrete[(size_t)row * KCODES + bi] = 1.0f;
    }
    __syncthreads();

    // ---- fused quantized gather: 32 rows x 16 float4, coalesced ----
#pragma unroll
    for (int e = t; e < RPB * 16; e += 256) {
        int r = e >> 4, c = e & 15;
        float4 v = *((const float4*)(cb + (size_t)sidx[r] * DDIM) + c);
        *((float4*)(quantized + (size_t)(row0 + r) * DDIM) + c) = v;
    }
}

extern "C" void kernel_launch(void* const* d_in, const int* in_sizes, int n_in,
                              void* d_out, int out_size, void* d_ws, size_t ws_size,
                              hipStream_t stream) {
    const float* x  = (const float*)d_in[0];   // 16*32*32*64
    const float* cb = (const float*)d_in[1];   // 8192*64

    float* discrete  = (float*)d_out;                          // 16384*8192
    float* quantized = (float*)d_out + (size_t)NROWS * KCODES; // 16384*64

    // workspace layout: cn2 (32 KB) | packed B-frags (2 MB).
    float* cn2    = (float*)d_ws;              // 8192 floats
    f16x8* packed = (f16x8*)(cn2 + KCODES);    // 2 MB

    k_prep<<<(KCODES / 16) * 64 / 256, 256, 0, stream>>>(cb, packed, cn2);
    k_main<<<NROWS / RPB, CWAVES * 64, 0, stream>>>(x, cb, packed, cn2,
                                                    discrete, quantized);
}